// Round 4
// baseline (36.383 us; speedup 1.0000x reference)
//
#include <hip/hip_runtime.h>
#include <math.h>

// Spe loss: per-pixel cosine-angle between x[:, :, h, w] and y[:, :, h, w]
// reduced over B*C=1024, then mean of acos over 144*144 pixels.
// Round 4: force MLP with explicit load cluster + sched_barrier(0)
// (VGPR was 32 = compiler re-serialized CHUNK=4), and fuse final into
// stage2 via deterministic last-block pattern (one fewer launch).

constexpr int PLANE  = 144 * 144;     // 20736 pixels per (b,c) plane (contiguous)
constexpr int QUADS  = PLANE / 4;     // 5184 float4 quads per plane
constexpr int BC     = 16 * 64;       // 1024 reduction depth
constexpr int SPLIT  = 8;             // bc splits across blockIdx.y (ws = 2 MB)
constexpr int BCS    = BC / SPLIT;    // 128 planes per split
constexpr int WAVES  = 8;             // waves per block
constexpr int PPW    = BCS / WAVES;   // 16 planes per wave
constexpr int CHUNK  = 8;             // planes loaded per ILP chunk (16 loads in flight)
constexpr int NCHUNK = PPW / CHUNK;   // 2 chunks
constexpr int NBLK   = QUADS / 64;    // 81 blocks in x (64 quads per block)
constexpr int B2     = 81;            // stage-2 blocks (81 * 256 = 20736 pixels)

__global__ __launch_bounds__(512) void spe_partial(const float4* __restrict__ x,
                                                   const float4* __restrict__ y,
                                                   float4* __restrict__ fzp,
                                                   float4* __restrict__ xxp,
                                                   float4* __restrict__ yyp,
                                                   unsigned* __restrict__ counter)
{
    const int tid  = threadIdx.x;
    const int lane = tid & 63;
    const int w    = tid >> 6;                 // wave: 0..7
    const int s    = blockIdx.y;               // bc split: 0..7
    const int qq   = blockIdx.x * 64 + lane;   // wave reads 1KB contiguous

    // Re-arm the stage-2 completion counter each call (kernel-boundary
    // coherence makes this visible to spe_stage2).
    if (blockIdx.x == 0 && blockIdx.y == 0 && tid == 0) *counter = 0u;

    float4 fz = make_float4(0.f, 0.f, 0.f, 0.f);
    float4 xx = make_float4(0.f, 0.f, 0.f, 0.f);
    float4 yy = make_float4(0.f, 0.f, 0.f, 0.f);

    // planes for this wave: p = s*BCS + i*WAVES + w, i = 0..PPW-1
    size_t idx = ((size_t)s * BCS + w) * QUADS + (size_t)qq;
    const size_t pstep = (size_t)WAVES * QUADS;    // advance 8 planes

    #pragma unroll 1
    for (int c = 0; c < NCHUNK; ++c) {
        float4 a[CHUNK], b[CHUNK];
        size_t i0 = idx;
        #pragma unroll
        for (int u = 0; u < CHUNK; ++u) {      // 16 loads issued back-to-back
            a[u] = x[i0];
            b[u] = y[i0];
            i0 += pstep;
        }
        // Fence: no FMA may be hoisted above, no load sunk below.
        __builtin_amdgcn_sched_barrier(0);
        #pragma unroll
        for (int u = 0; u < CHUNK; ++u) {
            fz.x = fmaf(a[u].x, b[u].x, fz.x); fz.y = fmaf(a[u].y, b[u].y, fz.y);
            fz.z = fmaf(a[u].z, b[u].z, fz.z); fz.w = fmaf(a[u].w, b[u].w, fz.w);
            xx.x = fmaf(a[u].x, a[u].x, xx.x); xx.y = fmaf(a[u].y, a[u].y, xx.y);
            xx.z = fmaf(a[u].z, a[u].z, xx.z); xx.w = fmaf(a[u].w, a[u].w, xx.w);
            yy.x = fmaf(b[u].x, b[u].x, yy.x); yy.y = fmaf(b[u].y, b[u].y, yy.y);
            yy.z = fmaf(b[u].z, b[u].z, yy.z); yy.w = fmaf(b[u].w, b[u].w, yy.w);
        }
        idx += pstep * CHUNK;
    }

    // Cross-wave fold: 8 waves each hold a partial for the same 64 quads.
    __shared__ float4 lf[WAVES][64], lx[WAVES][64], ly[WAVES][64];   // 24 KB
    lf[w][lane] = fz; lx[w][lane] = xx; ly[w][lane] = yy;
    __syncthreads();

    if (tid < 64) {
        float4 F = lf[0][tid], X = lx[0][tid], Y = ly[0][tid];
        #pragma unroll
        for (int wv = 1; wv < WAVES; ++wv) {
            F.x += lf[wv][tid].x; F.y += lf[wv][tid].y;
            F.z += lf[wv][tid].z; F.w += lf[wv][tid].w;
            X.x += lx[wv][tid].x; X.y += lx[wv][tid].y;
            X.z += lx[wv][tid].z; X.w += lx[wv][tid].w;
            Y.x += ly[wv][tid].x; Y.y += ly[wv][tid].y;
            Y.z += ly[wv][tid].z; Y.w += ly[wv][tid].w;
        }
        const size_t o = (size_t)s * QUADS + (size_t)(blockIdx.x * 64 + tid);
        fzp[o] = F; xxp[o] = X; yyp[o] = Y;
    }
}

__global__ __launch_bounds__(256) void spe_stage2(const float* __restrict__ fzp,
                                                  const float* __restrict__ xxp,
                                                  const float* __restrict__ yyp,
                                                  float* __restrict__ bsum,
                                                  unsigned* __restrict__ counter,
                                                  float* __restrict__ out)
{
    const int t = threadIdx.x;
    const int p = blockIdx.x * 256 + t;    // pixel index, 0..20735

    float F = 0.f, X = 0.f, Y = 0.f;
    #pragma unroll
    for (int s = 0; s < SPLIT; ++s) {
        F += fzp[s * PLANE + p];
        X += xxp[s * PLANE + p];
        Y += yyp[s * PLANE + p];
    }
    float r = F / (sqrtf(X) * sqrtf(Y));
    r = fminf(1.f, fmaxf(-1.f, r));
    float v = acosf(r);

    __shared__ float l[4];
    __shared__ int lastFlag;
    #pragma unroll
    for (int off = 32; off >= 1; off >>= 1) v += __shfl_down(v, off);
    if ((t & 63) == 0) l[t >> 6] = v;
    __syncthreads();

    if (t == 0) {
        bsum[blockIdx.x] = l[0] + l[1] + l[2] + l[3];
        __threadfence();                       // publish bsum before counting
        unsigned old = atomicAdd(counter, 1u);
        lastFlag = (old == B2 - 1);
    }
    __syncthreads();

    // Deterministic final: exactly one block runs this, in fixed index order.
    if (lastFlag && t == 0) {
        __threadfence();                       // acquire all bsum[]
        float tot = 0.f;
        for (int i = 0; i < B2; ++i) tot += bsum[i];
        out[0] = tot * (1.0f / (float)PLANE);
    }
}

extern "C" void kernel_launch(void* const* d_in, const int* in_sizes, int n_in,
                              void* d_out, int out_size, void* d_ws, size_t ws_size,
                              hipStream_t stream) {
    const float4* x = (const float4*)d_in[0];
    const float4* y = (const float4*)d_in[1];
    // d_in[2] is `shape` (=144, full extent — slicing is a no-op).

    float* ws   = (float*)d_ws;
    float* fzp  = ws;                                  // SPLIT * PLANE floats
    float* xxp  = ws + (size_t)SPLIT * PLANE;
    float* yyp  = ws + (size_t)2 * SPLIT * PLANE;
    float* bsum = ws + (size_t)3 * SPLIT * PLANE;      // 81 floats
    unsigned* counter = (unsigned*)(bsum + B2);        // 1 uint
    float* out  = (float*)d_out;

    dim3 grid(NBLK, SPLIT);
    spe_partial<<<grid, 512, 0, stream>>>(x, y, (float4*)fzp, (float4*)xxp,
                                          (float4*)yyp, counter);
    spe_stage2<<<B2, 256, 0, stream>>>(fzp, xxp, yyp, bsum, counter, out);
}

// Round 5
// 35.980 us; speedup vs baseline: 1.0112x; 1.0112x over previous
//
#include <hip/hip_runtime.h>
#include <math.h>

// Spe loss: per-pixel cosine-angle between x[:, :, h, w] and y[:, :, h, w]
// reduced over B*C=1024, then mean of acos over 144*144 pixels.
// Round 5: inline-asm global_load_dwordx4 + counted s_waitcnt vmcnt(4)
// software pipeline — compiler kept defeating source-level ILP (VGPR 32/36
// across rounds 2-4 = ~2 loads in flight per wave). Guarantees 8 outstanding
// 1KB wave-loads at all times. Distinguishes latency-bound vs fabric-ceiling.

constexpr int PLANE  = 144 * 144;     // 20736 pixels per (b,c) plane (contiguous)
constexpr int QUADS  = PLANE / 4;     // 5184 float4 quads per plane
constexpr int BC     = 16 * 64;       // 1024 reduction depth
constexpr int SPLIT  = 8;             // bc splits across blockIdx.y (ws = 2 MB)
constexpr int BCS    = BC / SPLIT;    // 128 planes per split
constexpr int WAVES  = 8;             // waves per block
constexpr int PPW    = BCS / WAVES;   // 16 planes per thread
constexpr int NBLK   = QUADS / 64;    // 81 blocks in x (64 quads per block)
constexpr int B2     = 81;            // stage-2 blocks (81 * 256 = 20736 pixels)
constexpr unsigned PSTRIDE = (unsigned)(WAVES * QUADS * 16);  // 663552 B: +8 planes

__device__ __forceinline__ float4 gload(const float* __restrict__ base, unsigned off) {
    float4 r;
    asm volatile("global_load_dwordx4 %0, %1, %2"
                 : "=v"(r)
                 : "v"(off), "s"(base)
                 : "memory");
    return r;
}

__device__ __forceinline__ void fmac3(const float4& a, const float4& b,
                                      float4& fz, float4& xx, float4& yy) {
    fz.x = fmaf(a.x, b.x, fz.x); fz.y = fmaf(a.y, b.y, fz.y);
    fz.z = fmaf(a.z, b.z, fz.z); fz.w = fmaf(a.w, b.w, fz.w);
    xx.x = fmaf(a.x, a.x, xx.x); xx.y = fmaf(a.y, a.y, xx.y);
    xx.z = fmaf(a.z, a.z, xx.z); xx.w = fmaf(a.w, a.w, xx.w);
    yy.x = fmaf(b.x, b.x, yy.x); yy.y = fmaf(b.y, b.y, yy.y);
    yy.z = fmaf(b.z, b.z, yy.z); yy.w = fmaf(b.w, b.w, yy.w);
}

__global__ __launch_bounds__(512) void spe_partial(const float* __restrict__ xf,
                                                   const float* __restrict__ yf,
                                                   float4* __restrict__ fzp,
                                                   float4* __restrict__ xxp,
                                                   float4* __restrict__ yyp,
                                                   unsigned* __restrict__ counter)
{
    const int tid  = threadIdx.x;
    const int lane = tid & 63;
    const int w    = tid >> 6;                 // wave: 0..7
    const int s    = blockIdx.y;               // bc split: 0..7
    const int qq   = blockIdx.x * 64 + lane;   // wave reads 1KB contiguous

    if (blockIdx.x == 0 && blockIdx.y == 0 && tid == 0) *counter = 0u;

    float4 fz = make_float4(0.f, 0.f, 0.f, 0.f);
    float4 xx = make_float4(0.f, 0.f, 0.f, 0.f);
    float4 yy = make_float4(0.f, 0.f, 0.f, 0.f);

    // planes for this thread: p(i) = s*BCS + i*WAVES + w, i = 0..15
    // byte offset of (p, qq): (p*QUADS + qq)*16
    unsigned off = (((unsigned)s * BCS + (unsigned)w) * QUADS + (unsigned)qq) * 16u;

    // Software pipeline: 4 chunks in buffers A/B, 2 plane-pairs (4 loads) each.
    float4 bx[2][2], by[2][2];
    // Prologue: issue chunks 0 and 1 (8 loads outstanding).
    #pragma unroll
    for (int k = 0; k < 2; ++k) {
        #pragma unroll
        for (int u = 0; u < 2; ++u) {
            bx[k][u] = gload(xf, off);
            by[k][u] = gload(yf, off);
            off += PSTRIDE;
        }
    }
    #pragma unroll
    for (int c = 0; c < 8; ++c) {           // 8 chunks of 2 planes = 16 planes
        if (c < 7) asm volatile("s_waitcnt vmcnt(4)" ::: "memory");
        else       asm volatile("s_waitcnt vmcnt(0)" ::: "memory");
        __builtin_amdgcn_sched_barrier(0);
        const int cur = c & 1;              // compile-time under full unroll
        #pragma unroll
        for (int u = 0; u < 2; ++u) fmac3(bx[cur][u], by[cur][u], fz, xx, yy);
        if (c < 6) {                        // reissue chunk c+2 into freed buffer
            #pragma unroll
            for (int u = 0; u < 2; ++u) {
                bx[cur][u] = gload(xf, off);
                by[cur][u] = gload(yf, off);
                off += PSTRIDE;
            }
        }
    }

    // Cross-wave fold: 8 waves each hold a partial for the same 64 quads.
    __shared__ float4 lf[WAVES][64], lx[WAVES][64], ly[WAVES][64];   // 24 KB
    lf[w][lane] = fz; lx[w][lane] = xx; ly[w][lane] = yy;
    __syncthreads();

    if (tid < 64) {
        float4 F = lf[0][tid], X = lx[0][tid], Y = ly[0][tid];
        #pragma unroll
        for (int wv = 1; wv < WAVES; ++wv) {
            F.x += lf[wv][tid].x; F.y += lf[wv][tid].y;
            F.z += lf[wv][tid].z; F.w += lf[wv][tid].w;
            X.x += lx[wv][tid].x; X.y += lx[wv][tid].y;
            X.z += lx[wv][tid].z; X.w += lx[wv][tid].w;
            Y.x += ly[wv][tid].x; Y.y += ly[wv][tid].y;
            Y.z += ly[wv][tid].z; Y.w += ly[wv][tid].w;
        }
        const size_t o = (size_t)s * QUADS + (size_t)(blockIdx.x * 64 + tid);
        fzp[o] = F; xxp[o] = X; yyp[o] = Y;
    }
}

__global__ __launch_bounds__(256) void spe_stage2(const float* __restrict__ fzp,
                                                  const float* __restrict__ xxp,
                                                  const float* __restrict__ yyp,
                                                  float* __restrict__ bsum,
                                                  unsigned* __restrict__ counter,
                                                  float* __restrict__ out)
{
    const int t = threadIdx.x;
    const int p = blockIdx.x * 256 + t;    // pixel index, 0..20735

    float F = 0.f, X = 0.f, Y = 0.f;
    #pragma unroll
    for (int s = 0; s < SPLIT; ++s) {
        F += fzp[s * PLANE + p];
        X += xxp[s * PLANE + p];
        Y += yyp[s * PLANE + p];
    }
    float r = F / (sqrtf(X) * sqrtf(Y));
    r = fminf(1.f, fmaxf(-1.f, r));
    float v = acosf(r);

    __shared__ float l[4];
    __shared__ int lastFlag;
    #pragma unroll
    for (int off = 32; off >= 1; off >>= 1) v += __shfl_down(v, off);
    if ((t & 63) == 0) l[t >> 6] = v;
    __syncthreads();

    if (t == 0) {
        bsum[blockIdx.x] = l[0] + l[1] + l[2] + l[3];
        __threadfence();                       // publish bsum before counting
        unsigned old = atomicAdd(counter, 1u);
        lastFlag = (old == B2 - 1);
    }
    __syncthreads();

    // Deterministic final: exactly one block, fixed summation order.
    if (lastFlag && t == 0) {
        __threadfence();
        float tot = 0.f;
        for (int i = 0; i < B2; ++i) tot += bsum[i];
        out[0] = tot * (1.0f / (float)PLANE);
    }
}

extern "C" void kernel_launch(void* const* d_in, const int* in_sizes, int n_in,
                              void* d_out, int out_size, void* d_ws, size_t ws_size,
                              hipStream_t stream) {
    const float* x = (const float*)d_in[0];
    const float* y = (const float*)d_in[1];
    // d_in[2] is `shape` (=144, full extent — slicing is a no-op).

    float* ws   = (float*)d_ws;
    float* fzp  = ws;                                  // SPLIT * PLANE floats
    float* xxp  = ws + (size_t)SPLIT * PLANE;
    float* yyp  = ws + (size_t)2 * SPLIT * PLANE;
    float* bsum = ws + (size_t)3 * SPLIT * PLANE;      // 81 floats
    unsigned* counter = (unsigned*)(bsum + B2);        // 1 uint
    float* out  = (float*)d_out;

    dim3 grid(NBLK, SPLIT);
    spe_partial<<<grid, 512, 0, stream>>>(x, y, (float4*)fzp, (float4*)xxp,
                                          (float4*)yyp, counter);
    spe_stage2<<<B2, 256, 0, stream>>>(fzp, xxp, yyp, bsum, counter, out);
}